// Round 5
// baseline (799.798 us; speedup 1.0000x reference)
//
#include <hip/hip_runtime.h>

#define BDIM 4
#define HDIM 16
#define SDIM 4096
#define DDIM 64
#define NBH (BDIM * HDIM)

#define BH_STRIDE (DDIM * DDIM + DDIM)      // 4160 floats: [kv 64x64][kone 64]
#define CHUNK_FLOATS (NBH * BH_STRIDE)      // 266240 floats = 1,064,960 B

__device__ __forceinline__ float phi_f(float x) {
    // elu(x)+1 = x+1 (x>0) else exp(x)
    return x > 0.0f ? x + 1.0f : __expf(x);
}

// -------- Phase 1 (round-5 redesign): kv[d][e] = sum_s phiK[s][d]*V[s][e]
// Waves split the E dimension: wave w owns cols [w*16, w*16+16) -> per-lane
// tile is 4x4 (d0=(l>>2)*4, e0=w*16+(l&3)*4), only 16 acc VGPRs, and NO
// cross-wave accumulator reduction (disjoint outputs). phiK staged in a
// SHARED 8 KB double-buffered tile (1 barrier/tile); each wave stages 4 of
// the 16 rows. V streams global->reg with an explicit vr[8] half-tile
// prefetch (>=8 loads in flight/wave; round-4 counters showed ~4 in flight,
// 2.0 TB/s delivered, latency-bound at VALUBusy 28%).
// __launch_bounds__(256,5): VGPR cap 102 -> 5 waves/SIMD (20 waves/CU).
template<bool ATOMIC>
__global__ __launch_bounds__(256, 5) void la_phase1(
    const float* __restrict__ K, const float* __restrict__ V,
    const float* __restrict__ mask, float* __restrict__ outp, int chunk_rows)
{
    __shared__ __align__(16) float kT[2][16][DDIM];   // 8 KB shared phiK tiles
    __shared__ __align__(16) float koneP[4][DDIM];    // 1 KB kone partials

    const int bh = blockIdx.y;
    const int b  = bh / HDIM;
    const int t  = threadIdx.x;
    const int w  = t >> 6;                  // wave 0..3
    const int l  = t & 63;
    const int srow = (w << 2) + (l >> 4);   // staging row 0..15 (4 per wave)
    const int c4   = (l & 15) << 2;         // staging col 0..60
    const int d0   = (l >> 2) << 2;         // compute: 4 d-rows
    const int e0   = (w << 4) + ((l & 3) << 2);   // compute: 4 e-cols in wave slice

    const float* Kb = K + (size_t)bh * SDIM * DDIM;
    const float* Vb = V + (size_t)bh * SDIM * DDIM;
    const float* mb = mask + (size_t)b * SDIM;
    const float scale = 0.35355339059327373f;   // 64^-0.25

    const int s_base = blockIdx.x * chunk_rows;
    const int ntiles = chunk_rows >> 4;

    float acc[4][4] = {};
    float k1s[4] = {0.f, 0.f, 0.f, 0.f};    // kone partial, cols c4..c4+3

    // stage tile 0
    {
        const int s = s_base + srow;
        const float4 kf = *(const float4*)(Kb + (size_t)s * DDIM + c4);
        const float  m  = mb[s];
        float4 p;
        p.x = phi_f(kf.x * scale) * m;
        p.y = phi_f(kf.y * scale) * m;
        p.z = phi_f(kf.z * scale) * m;
        p.w = phi_f(kf.w * scale) * m;
        k1s[0] += p.x; k1s[1] += p.y; k1s[2] += p.z; k1s[3] += p.w;
        *(float4*)&kT[0][srow][c4] = p;
    }
    __syncthreads();

    for (int tt = 0; tt < ntiles; ++tt) {
        const int cur = tt & 1;
        // issue next tile's K load first: retires under this tile's FMAs
        float4 kf; float mnext = 0.f;
        const bool more = (tt + 1 < ntiles);
        if (more) {
            const int s = s_base + ((tt + 1) << 4) + srow;
            kf = *(const float4*)(Kb + (size_t)s * DDIM + c4);
            mnext = mb[s];
        }

        const float* Vt = Vb + (size_t)(s_base + (tt << 4)) * DDIM + e0;
        // half-tile A: 8 V rows in flight, then 8x16 FMA
        float4 vr[8];
        #pragma unroll
        for (int ss = 0; ss < 8; ++ss) vr[ss] = *(const float4*)(Vt + (size_t)ss * DDIM);
        #pragma unroll
        for (int ss = 0; ss < 8; ++ss) {
            const float4 a = *(const float4*)&kT[cur][ss][d0];
            acc[0][0] += a.x * vr[ss].x; acc[0][1] += a.x * vr[ss].y; acc[0][2] += a.x * vr[ss].z; acc[0][3] += a.x * vr[ss].w;
            acc[1][0] += a.y * vr[ss].x; acc[1][1] += a.y * vr[ss].y; acc[1][2] += a.y * vr[ss].z; acc[1][3] += a.y * vr[ss].w;
            acc[2][0] += a.z * vr[ss].x; acc[2][1] += a.z * vr[ss].y; acc[2][2] += a.z * vr[ss].z; acc[2][3] += a.z * vr[ss].w;
            acc[3][0] += a.w * vr[ss].x; acc[3][1] += a.w * vr[ss].y; acc[3][2] += a.w * vr[ss].z; acc[3][3] += a.w * vr[ss].w;
        }
        // half-tile B
        #pragma unroll
        for (int ss = 0; ss < 8; ++ss) vr[ss] = *(const float4*)(Vt + (size_t)(ss + 8) * DDIM);
        #pragma unroll
        for (int ss = 0; ss < 8; ++ss) {
            const float4 a = *(const float4*)&kT[cur][ss + 8][d0];
            acc[0][0] += a.x * vr[ss].x; acc[0][1] += a.x * vr[ss].y; acc[0][2] += a.x * vr[ss].z; acc[0][3] += a.x * vr[ss].w;
            acc[1][0] += a.y * vr[ss].x; acc[1][1] += a.y * vr[ss].y; acc[1][2] += a.y * vr[ss].z; acc[1][3] += a.y * vr[ss].w;
            acc[2][0] += a.z * vr[ss].x; acc[2][1] += a.z * vr[ss].y; acc[2][2] += a.z * vr[ss].z; acc[2][3] += a.z * vr[ss].w;
            acc[3][0] += a.w * vr[ss].x; acc[3][1] += a.w * vr[ss].y; acc[3][2] += a.w * vr[ss].z; acc[3][3] += a.w * vr[ss].w;
        }

        // stage next tile into the other buffer (write != read buffer; the
        // end-of-iteration barrier publishes it and protects the swap)
        if (more) {
            float4 p;
            p.x = phi_f(kf.x * scale) * mnext;
            p.y = phi_f(kf.y * scale) * mnext;
            p.z = phi_f(kf.z * scale) * mnext;
            p.w = phi_f(kf.w * scale) * mnext;
            k1s[0] += p.x; k1s[1] += p.y; k1s[2] += p.z; k1s[3] += p.w;
            *(float4*)&kT[cur ^ 1][srow][c4] = p;
        }
        __syncthreads();
    }

    float* base = ATOMIC ? (outp + (size_t)bh * BH_STRIDE)
                         : (outp + ((size_t)blockIdx.x * NBH + bh) * BH_STRIDE);

    // acc: waves own disjoint (d,e) -> direct stores, no reduction
    if (ATOMIC) {
        #pragma unroll
        for (int i = 0; i < 4; ++i)
            #pragma unroll
            for (int j = 0; j < 4; ++j)
                atomicAdd(&base[(d0 + i) * DDIM + e0 + j], acc[i][j]);
    } else {
        #pragma unroll
        for (int i = 0; i < 4; ++i)
            *(float4*)&base[(d0 + i) * DDIM + e0] =
                make_float4(acc[i][0], acc[i][1], acc[i][2], acc[i][3]);
    }

    // kone: lanes {l, l^16, l^32, l^48} share c4 and cover the wave's 4
    // staged rows -> 2 shfls give per-wave col sums; tiny LDS combine.
    #pragma unroll
    for (int i = 0; i < 4; ++i) {
        k1s[i] += __shfl_xor(k1s[i], 16);
        k1s[i] += __shfl_xor(k1s[i], 32);
    }
    if (l < 16) *(float4*)&koneP[w][c4] = make_float4(k1s[0], k1s[1], k1s[2], k1s[3]);
    __syncthreads();
    if (t < DDIM) {
        const float s1 = koneP[0][t] + koneP[1][t] + koneP[2][t] + koneP[3][t];
        if (ATOMIC) atomicAdd(&base[DDIM * DDIM + t], s1);
        else        base[DDIM * DDIM + t] = s1;
    }
}

// -------- Reduce: fin[i] = sum_c part[c][i]; compile-time NC -> all loads in flight
template<int NCT>
__global__ __launch_bounds__(256) void la_reduce(
    const float* __restrict__ part, float* __restrict__ fin)
{
    const int g = blockIdx.x * 256 + threadIdx.x;     // float4 index
    const float4* p4 = (const float4*)part;
    float4 s = p4[g];
    #pragma unroll
    for (int c = 1; c < NCT; ++c) {
        const float4 v = p4[(size_t)c * (CHUNK_FLOATS / 4) + g];
        s.x += v.x; s.y += v.y; s.z += v.z; s.w += v.w;
    }
    ((float4*)fin)[g] = s;
}

// -------- Phase 2: out[s][e] = (sum_d phiQ[s][d]*kv[d][e]) * mm / (mm*sum_d phiQ[s][d]*kone[d] + 1e-8)
// (unchanged from round 4: 55-60 us, out of top-5)
// 256 threads = 4 waves; block covers 128 q-rows (wave w: rows w*32..+32).
// Lane tile 4 rows x 8 cols. Per dt: lane loads ONE distinct row, phi's it,
// publishes to wave-private LDS (double-buffered, in-wave DS ordering -> no
// barrier); a-operand returns as ds_read_b128 broadcast.
__global__ __launch_bounds__(256, 4) void la_phase2(
    const float* __restrict__ Q, const float* __restrict__ mask,
    const float* __restrict__ fin_all, float* __restrict__ out)
{
    __shared__ __align__(16) float kvL[DDIM * DDIM];   // 16 KB
    __shared__ __align__(16) float koL[DDIM];
    __shared__ __align__(16) float pqw[4][2][32][4];   // 4 KB phi(Q) staging

    const int bh = blockIdx.y;
    const int b  = bh / HDIM;
    const int t  = threadIdx.x;
    const int w  = t >> 6;
    const int l  = t & 63;
    const int g  = l >> 3;                  // row group 0..7 (4 rows each)
    const int e0 = (l & 7) << 3;
    const int rbase = blockIdx.x * 128 + (w << 5);   // wave's 32 rows
    const int rown  = l & 31;               // row this lane loads (dup for l>=32)

    const float* fin = fin_all + (size_t)bh * BH_STRIDE;
    {
        const float4* src = (const float4*)fin;
        float4* dst = (float4*)kvL;
        #pragma unroll
        for (int k2 = 0; k2 < 4; ++k2) dst[t + 256 * k2] = src[t + 256 * k2];
        if (t < DDIM) koL[t] = fin[DDIM * DDIM + t];
    }

    const float* Qb   = Q + (size_t)bh * SDIM * DDIM;
    const float* mb   = mask + (size_t)b * SDIM;
    const float* Qrow = Qb + (size_t)(rbase + rown) * DDIM;
    const float scale = 0.35355339059327373f;

    // prologue loads overlap the kv-staging barrier
    float4 q0 = *(const float4*)(Qrow);      // dt=0
    float4 qn = *(const float4*)(Qrow + 4);  // dt=1
    __syncthreads();

    // stage dt=0's phi into buf 0 (wave-private; in-wave ordering suffices)
    {
        float4 p;
        p.x = phi_f(q0.x * scale);
        p.y = phi_f(q0.y * scale);
        p.z = phi_f(q0.z * scale);
        p.w = phi_f(q0.w * scale);
        if (l < 32) *(float4*)&pqw[w][0][rown][0] = p;
    }

    float acc[4][8] = {};
    float nrm[4] = {0.f, 0.f, 0.f, 0.f};

    #pragma unroll 1
    for (int dt = 0; dt < 16; ++dt) {
        const int d4  = dt << 2;
        const int cur = dt & 1;
        // stage next dt's phi into the other buffer; prefetch dt+2's Q
        if (dt < 15) {
            float4 p;
            p.x = phi_f(qn.x * scale);
            p.y = phi_f(qn.y * scale);
            p.z = phi_f(qn.z * scale);
            p.w = phi_f(qn.w * scale);
            if (l < 32) *(float4*)&pqw[w][cur ^ 1][rown][0] = p;
            if (dt < 14) qn = *(const float4*)(Qrow + ((dt + 2) << 2));
        }
        // a-rows for this dt (written by this wave at dt-1; in-order DS)
        float4 ar[4];
        #pragma unroll
        for (int i = 0; i < 4; ++i)
            ar[i] = *(const float4*)&pqw[w][cur][(g << 2) + i][0];
        const float4 ko4 = *(const float4*)&koL[d4];
        #pragma unroll
        for (int dd = 0; dd < 4; ++dd) {
            const float4 b0 = *(const float4*)&kvL[(d4 + dd) * DDIM + e0];
            const float4 b1 = *(const float4*)&kvL[(d4 + dd) * DDIM + e0 + 4];
            const float kod = (dd == 0) ? ko4.x : (dd == 1) ? ko4.y : (dd == 2) ? ko4.z : ko4.w;
            #pragma unroll
            for (int i = 0; i < 4; ++i) {
                const float a = (dd == 0) ? ar[i].x : (dd == 1) ? ar[i].y : (dd == 2) ? ar[i].z : ar[i].w;
                nrm[i] += a * kod;
                acc[i][0] += a * b0.x; acc[i][1] += a * b0.y; acc[i][2] += a * b0.z; acc[i][3] += a * b0.w;
                acc[i][4] += a * b1.x; acc[i][5] += a * b1.y; acc[i][6] += a * b1.z; acc[i][7] += a * b1.w;
            }
        }
    }

    // mask folds in exactly: out = mm*A / (mm*B + 1e-8)
    float* ob = out + (size_t)bh * SDIM * DDIM;
    #pragma unroll
    for (int i = 0; i < 4; ++i) {
        const int r  = rbase + (g << 2) + i;
        const float mm  = mb[r];
        const float inv = mm / (mm * nrm[i] + 1e-8f);
        *(float4*)(ob + (size_t)r * DDIM + e0) =
            make_float4(acc[i][0] * inv, acc[i][1] * inv, acc[i][2] * inv, acc[i][3] * inv);
        *(float4*)(ob + (size_t)r * DDIM + e0 + 4) =
            make_float4(acc[i][4] * inv, acc[i][5] * inv, acc[i][6] * inv, acc[i][7] * inv);
    }
}

extern "C" void kernel_launch(void* const* d_in, const int* in_sizes, int n_in,
                              void* d_out, int out_size, void* d_ws, size_t ws_size,
                              hipStream_t stream) {
    const float* Q = (const float*)d_in[0];
    const float* K = (const float*)d_in[1];
    const float* V = (const float*)d_in[2];
    const float* M = (const float*)d_in[3];
    float* out = (float*)d_out;

    const size_t chunk_bytes = (size_t)CHUNK_FLOATS * sizeof(float);  // 1,064,960 B

    // ws_size is constant across calls -> same path every call (graph-safe)
    if (ws_size >= 33 * chunk_bytes) {          // 35.1 MB: 32 partials + final
        float* part = (float*)d_ws;
        float* fin  = part + (size_t)32 * CHUNK_FLOATS;
        la_phase1<false><<<dim3(32, NBH), dim3(256), 0, stream>>>(K, V, M, part, SDIM / 32);
        la_reduce<32><<<dim3(CHUNK_FLOATS / 4 / 256), dim3(256), 0, stream>>>(part, fin);
        la_phase2<<<dim3(SDIM / 128, NBH), dim3(256), 0, stream>>>(Q, M, fin, out);
    } else if (ws_size >= 17 * chunk_bytes) {   // 18.1 MB: 16 partials + final
        float* part = (float*)d_ws;
        float* fin  = part + (size_t)16 * CHUNK_FLOATS;
        la_phase1<false><<<dim3(16, NBH), dim3(256), 0, stream>>>(K, V, M, part, SDIM / 16);
        la_reduce<16><<<dim3(CHUNK_FLOATS / 4 / 256), dim3(256), 0, stream>>>(part, fin);
        la_phase2<<<dim3(SDIM / 128, NBH), dim3(256), 0, stream>>>(Q, M, fin, out);
    } else {
        // fallback: atomic accumulation directly into final buffer (1.06 MB)
        float* fin = (float*)d_ws;
        hipMemsetAsync(d_ws, 0, chunk_bytes, stream);
        la_phase1<true><<<dim3(16, NBH), dim3(256), 0, stream>>>(K, V, M, fin, SDIM / 16);
        la_phase2<<<dim3(SDIM / 128, NBH), dim3(256), 0, stream>>>(Q, M, fin, out);
    }
}

// Round 6
// 527.382 us; speedup vs baseline: 1.5165x; 1.5165x over previous
//
#include <hip/hip_runtime.h>

#define BDIM 4
#define HDIM 16
#define SDIM 4096
#define DDIM 64
#define NBH (BDIM * HDIM)

#define BH_STRIDE (DDIM * DDIM + DDIM)      // 4160 floats: [kv 64x64][kone 64]
#define CHUNK_FLOATS (NBH * BH_STRIDE)      // 266240 floats = 1,064,960 B

__device__ __forceinline__ float phi_f(float x) {
    // elu(x)+1 = x+1 (x>0) else exp(x)
    return x > 0.0f ? x + 1.0f : __expf(x);
}

// -------- Phase 1: kv[d][e] = sum_s phiK[s][d]*V[s][e]; kone[d] = sum_s phiK[s][d]
// Waves split the E dimension: wave w owns cols [w*16, w*16+16) -> per-lane
// tile is 4x4 (16 acc VGPRs), NO cross-wave accumulator reduction. phiK
// staged in a SHARED 8 KB double-buffered tile (1 barrier/tile). V streams
// global->reg with an explicit vr[8] half-tile prefetch (8 loads in flight).
// __launch_bounds__(256, 4): VGPR cap 128. Need ~85 -> fits, 4 waves/SIMD.
//   round-5 lesson: (256,5) forced a sub-64 VGPR class (measured 48) ->
//   2.2 GB scratch traffic, 620 us. gfx950 occupancy steps at 64/128/256;
//   pick the step ABOVE the register need, never between steps.
template<bool ATOMIC>
__global__ __launch_bounds__(256, 4) void la_phase1(
    const float* __restrict__ K, const float* __restrict__ V,
    const float* __restrict__ mask, float* __restrict__ outp, int chunk_rows)
{
    __shared__ __align__(16) float kT[2][16][DDIM];   // 8 KB shared phiK tiles
    __shared__ __align__(16) float koneP[4][DDIM];    // 1 KB kone partials

    const int bh = blockIdx.y;
    const int b  = bh / HDIM;
    const int t  = threadIdx.x;
    const int w  = t >> 6;                  // wave 0..3
    const int l  = t & 63;
    const int srow = (w << 2) + (l >> 4);   // staging row 0..15 (4 per wave)
    const int c4   = (l & 15) << 2;         // staging col 0..60
    const int d0   = (l >> 2) << 2;         // compute: 4 d-rows
    const int e0   = (w << 4) + ((l & 3) << 2);   // compute: 4 e-cols in wave slice

    const float* Kb = K + (size_t)bh * SDIM * DDIM;
    const float* Vb = V + (size_t)bh * SDIM * DDIM;
    const float* mb = mask + (size_t)b * SDIM;
    const float scale = 0.35355339059327373f;   // 64^-0.25

    const int s_base = blockIdx.x * chunk_rows;
    const int ntiles = chunk_rows >> 4;

    float acc[4][4] = {};
    float k1s[4] = {0.f, 0.f, 0.f, 0.f};    // kone partial, cols c4..c4+3

    // stage tile 0
    {
        const int s = s_base + srow;
        const float4 kf = *(const float4*)(Kb + (size_t)s * DDIM + c4);
        const float  m  = mb[s];
        float4 p;
        p.x = phi_f(kf.x * scale) * m;
        p.y = phi_f(kf.y * scale) * m;
        p.z = phi_f(kf.z * scale) * m;
        p.w = phi_f(kf.w * scale) * m;
        k1s[0] += p.x; k1s[1] += p.y; k1s[2] += p.z; k1s[3] += p.w;
        *(float4*)&kT[0][srow][c4] = p;
    }
    __syncthreads();

    for (int tt = 0; tt < ntiles; ++tt) {
        const int cur = tt & 1;
        // issue next tile's K load first: retires under this tile's FMAs
        float4 kf; float mnext = 0.f;
        const bool more = (tt + 1 < ntiles);
        if (more) {
            const int s = s_base + ((tt + 1) << 4) + srow;
            kf = *(const float4*)(Kb + (size_t)s * DDIM + c4);
            mnext = mb[s];
        }

        const float* Vt = Vb + (size_t)(s_base + (tt << 4)) * DDIM + e0;
        // half-tile A: 8 V rows in flight, then 8x16 FMA
        float4 vr[8];
        #pragma unroll
        for (int ss = 0; ss < 8; ++ss) vr[ss] = *(const float4*)(Vt + (size_t)ss * DDIM);
        #pragma unroll
        for (int ss = 0; ss < 8; ++ss) {
            const float4 a = *(const float4*)&kT[cur][ss][d0];
            acc[0][0] += a.x * vr[ss].x; acc[0][1] += a.x * vr[ss].y; acc[0][2] += a.x * vr[ss].z; acc[0][3] += a.x * vr[ss].w;
            acc[1][0] += a.y * vr[ss].x; acc[1][1] += a.y * vr[ss].y; acc[1][2] += a.y * vr[ss].z; acc[1][3] += a.y * vr[ss].w;
            acc[2][0] += a.z * vr[ss].x; acc[2][1] += a.z * vr[ss].y; acc[2][2] += a.z * vr[ss].z; acc[2][3] += a.z * vr[ss].w;
            acc[3][0] += a.w * vr[ss].x; acc[3][1] += a.w * vr[ss].y; acc[3][2] += a.w * vr[ss].z; acc[3][3] += a.w * vr[ss].w;
        }
        // half-tile B
        #pragma unroll
        for (int ss = 0; ss < 8; ++ss) vr[ss] = *(const float4*)(Vt + (size_t)(ss + 8) * DDIM);
        #pragma unroll
        for (int ss = 0; ss < 8; ++ss) {
            const float4 a = *(const float4*)&kT[cur][ss + 8][d0];
            acc[0][0] += a.x * vr[ss].x; acc[0][1] += a.x * vr[ss].y; acc[0][2] += a.x * vr[ss].z; acc[0][3] += a.x * vr[ss].w;
            acc[1][0] += a.y * vr[ss].x; acc[1][1] += a.y * vr[ss].y; acc[1][2] += a.y * vr[ss].z; acc[1][3] += a.y * vr[ss].w;
            acc[2][0] += a.z * vr[ss].x; acc[2][1] += a.z * vr[ss].y; acc[2][2] += a.z * vr[ss].z; acc[2][3] += a.z * vr[ss].w;
            acc[3][0] += a.w * vr[ss].x; acc[3][1] += a.w * vr[ss].y; acc[3][2] += a.w * vr[ss].z; acc[3][3] += a.w * vr[ss].w;
        }

        // stage next tile into the other buffer (write != read buffer; the
        // end-of-iteration barrier publishes it and protects the swap)
        if (more) {
            float4 p;
            p.x = phi_f(kf.x * scale) * mnext;
            p.y = phi_f(kf.y * scale) * mnext;
            p.z = phi_f(kf.z * scale) * mnext;
            p.w = phi_f(kf.w * scale) * mnext;
            k1s[0] += p.x; k1s[1] += p.y; k1s[2] += p.z; k1s[3] += p.w;
            *(float4*)&kT[cur ^ 1][srow][c4] = p;
        }
        __syncthreads();
    }

    float* base = ATOMIC ? (outp + (size_t)bh * BH_STRIDE)
                         : (outp + ((size_t)blockIdx.x * NBH + bh) * BH_STRIDE);

    // acc: waves own disjoint (d,e) -> direct stores, no reduction
    if (ATOMIC) {
        #pragma unroll
        for (int i = 0; i < 4; ++i)
            #pragma unroll
            for (int j = 0; j < 4; ++j)
                atomicAdd(&base[(d0 + i) * DDIM + e0 + j], acc[i][j]);
    } else {
        #pragma unroll
        for (int i = 0; i < 4; ++i)
            *(float4*)&base[(d0 + i) * DDIM + e0] =
                make_float4(acc[i][0], acc[i][1], acc[i][2], acc[i][3]);
    }

    // kone: lanes {l, l^16, l^32, l^48} share c4 and cover the wave's 4
    // staged rows -> 2 shfls give per-wave col sums; tiny LDS combine.
    #pragma unroll
    for (int i = 0; i < 4; ++i) {
        k1s[i] += __shfl_xor(k1s[i], 16);
        k1s[i] += __shfl_xor(k1s[i], 32);
    }
    if (l < 16) *(float4*)&koneP[w][c4] = make_float4(k1s[0], k1s[1], k1s[2], k1s[3]);
    __syncthreads();
    if (t < DDIM) {
        const float s1 = koneP[0][t] + koneP[1][t] + koneP[2][t] + koneP[3][t];
        if (ATOMIC) atomicAdd(&base[DDIM * DDIM + t], s1);
        else        base[DDIM * DDIM + t] = s1;
    }
}

// -------- Reduce: fin[i] = sum_c part[c][i]; compile-time NC -> all loads in flight
template<int NCT>
__global__ __launch_bounds__(256) void la_reduce(
    const float* __restrict__ part, float* __restrict__ fin)
{
    const int g = blockIdx.x * 256 + threadIdx.x;     // float4 index
    const float4* p4 = (const float4*)part;
    float4 s = p4[g];
    #pragma unroll
    for (int c = 1; c < NCT; ++c) {
        const float4 v = p4[(size_t)c * (CHUNK_FLOATS / 4) + g];
        s.x += v.x; s.y += v.y; s.z += v.z; s.w += v.w;
    }
    ((float4*)fin)[g] = s;
}

// -------- Phase 2: out[s][e] = (sum_d phiQ[s][d]*kv[d][e]) * mm / (mm*sum_d phiQ[s][d]*kone[d] + 1e-8)
// (unchanged from round 4: out of top-5)
__global__ __launch_bounds__(256, 4) void la_phase2(
    const float* __restrict__ Q, const float* __restrict__ mask,
    const float* __restrict__ fin_all, float* __restrict__ out)
{
    __shared__ __align__(16) float kvL[DDIM * DDIM];   // 16 KB
    __shared__ __align__(16) float koL[DDIM];
    __shared__ __align__(16) float pqw[4][2][32][4];   // 4 KB phi(Q) staging

    const int bh = blockIdx.y;
    const int b  = bh / HDIM;
    const int t  = threadIdx.x;
    const int w  = t >> 6;
    const int l  = t & 63;
    const int g  = l >> 3;                  // row group 0..7 (4 rows each)
    const int e0 = (l & 7) << 3;
    const int rbase = blockIdx.x * 128 + (w << 5);   // wave's 32 rows
    const int rown  = l & 31;               // row this lane loads (dup for l>=32)

    const float* fin = fin_all + (size_t)bh * BH_STRIDE;
    {
        const float4* src = (const float4*)fin;
        float4* dst = (float4*)kvL;
        #pragma unroll
        for (int k2 = 0; k2 < 4; ++k2) dst[t + 256 * k2] = src[t + 256 * k2];
        if (t < DDIM) koL[t] = fin[DDIM * DDIM + t];
    }

    const float* Qb   = Q + (size_t)bh * SDIM * DDIM;
    const float* mb   = mask + (size_t)b * SDIM;
    const float* Qrow = Qb + (size_t)(rbase + rown) * DDIM;
    const float scale = 0.35355339059327373f;

    // prologue loads overlap the kv-staging barrier
    float4 q0 = *(const float4*)(Qrow);      // dt=0
    float4 qn = *(const float4*)(Qrow + 4);  // dt=1
    __syncthreads();

    // stage dt=0's phi into buf 0 (wave-private; in-wave ordering suffices)
    {
        float4 p;
        p.x = phi_f(q0.x * scale);
        p.y = phi_f(q0.y * scale);
        p.z = phi_f(q0.z * scale);
        p.w = phi_f(q0.w * scale);
        if (l < 32) *(float4*)&pqw[w][0][rown][0] = p;
    }

    float acc[4][8] = {};
    float nrm[4] = {0.f, 0.f, 0.f, 0.f};

    #pragma unroll 1
    for (int dt = 0; dt < 16; ++dt) {
        const int d4  = dt << 2;
        const int cur = dt & 1;
        // stage next dt's phi into the other buffer; prefetch dt+2's Q
        if (dt < 15) {
            float4 p;
            p.x = phi_f(qn.x * scale);
            p.y = phi_f(qn.y * scale);
            p.z = phi_f(qn.z * scale);
            p.w = phi_f(qn.w * scale);
            if (l < 32) *(float4*)&pqw[w][cur ^ 1][rown][0] = p;
            if (dt < 14) qn = *(const float4*)(Qrow + ((dt + 2) << 2));
        }
        // a-rows for this dt (written by this wave at dt-1; in-order DS)
        float4 ar[4];
        #pragma unroll
        for (int i = 0; i < 4; ++i)
            ar[i] = *(const float4*)&pqw[w][cur][(g << 2) + i][0];
        const float4 ko4 = *(const float4*)&koL[d4];
        #pragma unroll
        for (int dd = 0; dd < 4; ++dd) {
            const float4 b0 = *(const float4*)&kvL[(d4 + dd) * DDIM + e0];
            const float4 b1 = *(const float4*)&kvL[(d4 + dd) * DDIM + e0 + 4];
            const float kod = (dd == 0) ? ko4.x : (dd == 1) ? ko4.y : (dd == 2) ? ko4.z : ko4.w;
            #pragma unroll
            for (int i = 0; i < 4; ++i) {
                const float a = (dd == 0) ? ar[i].x : (dd == 1) ? ar[i].y : (dd == 2) ? ar[i].z : ar[i].w;
                nrm[i] += a * kod;
                acc[i][0] += a * b0.x; acc[i][1] += a * b0.y; acc[i][2] += a * b0.z; acc[i][3] += a * b0.w;
                acc[i][4] += a * b1.x; acc[i][5] += a * b1.y; acc[i][6] += a * b1.z; acc[i][7] += a * b1.w;
            }
        }
    }

    // mask folds in exactly: out = mm*A / (mm*B + 1e-8)
    float* ob = out + (size_t)bh * SDIM * DDIM;
    #pragma unroll
    for (int i = 0; i < 4; ++i) {
        const int r  = rbase + (g << 2) + i;
        const float mm  = mb[r];
        const float inv = mm / (mm * nrm[i] + 1e-8f);
        *(float4*)(ob + (size_t)r * DDIM + e0) =
            make_float4(acc[i][0] * inv, acc[i][1] * inv, acc[i][2] * inv, acc[i][3] * inv);
        *(float4*)(ob + (size_t)r * DDIM + e0 + 4) =
            make_float4(acc[i][4] * inv, acc[i][5] * inv, acc[i][6] * inv, acc[i][7] * inv);
    }
}

extern "C" void kernel_launch(void* const* d_in, const int* in_sizes, int n_in,
                              void* d_out, int out_size, void* d_ws, size_t ws_size,
                              hipStream_t stream) {
    const float* Q = (const float*)d_in[0];
    const float* K = (const float*)d_in[1];
    const float* V = (const float*)d_in[2];
    const float* M = (const float*)d_in[3];
    float* out = (float*)d_out;

    const size_t chunk_bytes = (size_t)CHUNK_FLOATS * sizeof(float);  // 1,064,960 B

    // ws_size is constant across calls -> same path every call (graph-safe)
    if (ws_size >= 33 * chunk_bytes) {          // 35.1 MB: 32 partials + final
        float* part = (float*)d_ws;
        float* fin  = part + (size_t)32 * CHUNK_FLOATS;
        la_phase1<false><<<dim3(32, NBH), dim3(256), 0, stream>>>(K, V, M, part, SDIM / 32);
        la_reduce<32><<<dim3(CHUNK_FLOATS / 4 / 256), dim3(256), 0, stream>>>(part, fin);
        la_phase2<<<dim3(SDIM / 128, NBH), dim3(256), 0, stream>>>(Q, M, fin, out);
    } else if (ws_size >= 17 * chunk_bytes) {   // 18.1 MB: 16 partials + final
        float* part = (float*)d_ws;
        float* fin  = part + (size_t)16 * CHUNK_FLOATS;
        la_phase1<false><<<dim3(16, NBH), dim3(256), 0, stream>>>(K, V, M, part, SDIM / 16);
        la_reduce<16><<<dim3(CHUNK_FLOATS / 4 / 256), dim3(256), 0, stream>>>(part, fin);
        la_phase2<<<dim3(SDIM / 128, NBH), dim3(256), 0, stream>>>(Q, M, fin, out);
    } else {
        // fallback: atomic accumulation directly into final buffer (1.06 MB)
        float* fin = (float*)d_ws;
        hipMemsetAsync(d_ws, 0, chunk_bytes, stream);
        la_phase1<true><<<dim3(16, NBH), dim3(256), 0, stream>>>(K, V, M, fin, SDIM / 16);
        la_phase2<<<dim3(SDIM / 128, NBH), dim3(256), 0, stream>>>(Q, M, fin, out);
    }
}

// Round 7
// 278.086 us; speedup vs baseline: 2.8761x; 1.8965x over previous
//
#include <hip/hip_runtime.h>

#define BDIM 4
#define HDIM 16
#define SDIM 4096
#define DDIM 64
#define NBH (BDIM * HDIM)

#define BH_STRIDE (DDIM * DDIM + DDIM)      // 4160 floats: [kv 64x64][kone 64]
#define CHUNK_FLOATS (NBH * BH_STRIDE)      // 266240 floats = 1,064,960 B

__device__ __forceinline__ float phi_f(float x) {
    // elu(x)+1 = x+1 (x>0) else exp(x)
    return x > 0.0f ? x + 1.0f : __expf(x);
}

// -------- Phase 1: kv[d][e] = sum_s phiK[s][d]*V[s][e]; kone[d] = sum_s phiK[s][d]
// Waves split the E dimension: wave w owns cols [w*16, w*16+16) -> per-lane
// tile is 4x4 (16 acc VGPRs), NO cross-wave accumulator reduction. phiK
// staged in a SHARED 8 KB double-buffered tile (1 barrier/tile). V streams
// global->reg with an explicit vr[8] half-tile prefetch (8 loads in flight).
//
// LAUNCH-BOUNDS RULE (rounds 1/4/5/6, measured): on this toolchain the arch-
// VGPR grant is ~half of 512/n -- (256,2)->128-class (112 measured, no
// spill), (256,4)->64 (spills), (256,5)->48 (spills). This kernel needs
// ~85-95 regs => (256,2) is the ONLY bound that fits. Do not raise n.
template<bool ATOMIC>
__global__ __launch_bounds__(256, 2) void la_phase1(
    const float* __restrict__ K, const float* __restrict__ V,
    const float* __restrict__ mask, float* __restrict__ outp, int chunk_rows)
{
    __shared__ __align__(16) float kT[2][16][DDIM];   // 8 KB shared phiK tiles
    __shared__ __align__(16) float koneP[4][DDIM];    // 1 KB kone partials

    const int bh = blockIdx.y;
    const int b  = bh / HDIM;
    const int t  = threadIdx.x;
    const int w  = t >> 6;                  // wave 0..3
    const int l  = t & 63;
    const int srow = (w << 2) + (l >> 4);   // staging row 0..15 (4 per wave)
    const int c4   = (l & 15) << 2;         // staging col 0..60
    const int d0   = (l >> 2) << 2;         // compute: 4 d-rows
    const int e0   = (w << 4) + ((l & 3) << 2);   // compute: 4 e-cols in wave slice

    const float* Kb = K + (size_t)bh * SDIM * DDIM;
    const float* Vb = V + (size_t)bh * SDIM * DDIM;
    const float* mb = mask + (size_t)b * SDIM;
    const float scale = 0.35355339059327373f;   // 64^-0.25

    const int s_base = blockIdx.x * chunk_rows;
    const int ntiles = chunk_rows >> 4;

    float acc[4][4] = {};
    float k1s[4] = {0.f, 0.f, 0.f, 0.f};    // kone partial, cols c4..c4+3

    // stage tile 0
    {
        const int s = s_base + srow;
        const float4 kf = *(const float4*)(Kb + (size_t)s * DDIM + c4);
        const float  m  = mb[s];
        float4 p;
        p.x = phi_f(kf.x * scale) * m;
        p.y = phi_f(kf.y * scale) * m;
        p.z = phi_f(kf.z * scale) * m;
        p.w = phi_f(kf.w * scale) * m;
        k1s[0] += p.x; k1s[1] += p.y; k1s[2] += p.z; k1s[3] += p.w;
        *(float4*)&kT[0][srow][c4] = p;
    }
    __syncthreads();

    for (int tt = 0; tt < ntiles; ++tt) {
        const int cur = tt & 1;
        // issue next tile's K load first: retires under this tile's FMAs
        float4 kf; float mnext = 0.f;
        const bool more = (tt + 1 < ntiles);
        if (more) {
            const int s = s_base + ((tt + 1) << 4) + srow;
            kf = *(const float4*)(Kb + (size_t)s * DDIM + c4);
            mnext = mb[s];
        }

        const float* Vt = Vb + (size_t)(s_base + (tt << 4)) * DDIM + e0;
        // half-tile A: 8 V rows in flight, then 8x16 FMA
        float4 vr[8];
        #pragma unroll
        for (int ss = 0; ss < 8; ++ss) vr[ss] = *(const float4*)(Vt + (size_t)ss * DDIM);
        #pragma unroll
        for (int ss = 0; ss < 8; ++ss) {
            const float4 a = *(const float4*)&kT[cur][ss][d0];
            acc[0][0] += a.x * vr[ss].x; acc[0][1] += a.x * vr[ss].y; acc[0][2] += a.x * vr[ss].z; acc[0][3] += a.x * vr[ss].w;
            acc[1][0] += a.y * vr[ss].x; acc[1][1] += a.y * vr[ss].y; acc[1][2] += a.y * vr[ss].z; acc[1][3] += a.y * vr[ss].w;
            acc[2][0] += a.z * vr[ss].x; acc[2][1] += a.z * vr[ss].y; acc[2][2] += a.z * vr[ss].z; acc[2][3] += a.z * vr[ss].w;
            acc[3][0] += a.w * vr[ss].x; acc[3][1] += a.w * vr[ss].y; acc[3][2] += a.w * vr[ss].z; acc[3][3] += a.w * vr[ss].w;
        }
        // half-tile B
        #pragma unroll
        for (int ss = 0; ss < 8; ++ss) vr[ss] = *(const float4*)(Vt + (size_t)(ss + 8) * DDIM);
        #pragma unroll
        for (int ss = 0; ss < 8; ++ss) {
            const float4 a = *(const float4*)&kT[cur][ss + 8][d0];
            acc[0][0] += a.x * vr[ss].x; acc[0][1] += a.x * vr[ss].y; acc[0][2] += a.x * vr[ss].z; acc[0][3] += a.x * vr[ss].w;
            acc[1][0] += a.y * vr[ss].x; acc[1][1] += a.y * vr[ss].y; acc[1][2] += a.y * vr[ss].z; acc[1][3] += a.y * vr[ss].w;
            acc[2][0] += a.z * vr[ss].x; acc[2][1] += a.z * vr[ss].y; acc[2][2] += a.z * vr[ss].z; acc[2][3] += a.z * vr[ss].w;
            acc[3][0] += a.w * vr[ss].x; acc[3][1] += a.w * vr[ss].y; acc[3][2] += a.w * vr[ss].z; acc[3][3] += a.w * vr[ss].w;
        }

        // stage next tile into the other buffer (write != read buffer; the
        // end-of-iteration barrier publishes it and protects the swap)
        if (more) {
            float4 p;
            p.x = phi_f(kf.x * scale) * mnext;
            p.y = phi_f(kf.y * scale) * mnext;
            p.z = phi_f(kf.z * scale) * mnext;
            p.w = phi_f(kf.w * scale) * mnext;
            k1s[0] += p.x; k1s[1] += p.y; k1s[2] += p.z; k1s[3] += p.w;
            *(float4*)&kT[cur ^ 1][srow][c4] = p;
        }
        __syncthreads();
    }

    float* base = ATOMIC ? (outp + (size_t)bh * BH_STRIDE)
                         : (outp + ((size_t)blockIdx.x * NBH + bh) * BH_STRIDE);

    // acc: waves own disjoint (d,e) -> direct stores, no reduction
    if (ATOMIC) {
        #pragma unroll
        for (int i = 0; i < 4; ++i)
            #pragma unroll
            for (int j = 0; j < 4; ++j)
                atomicAdd(&base[(d0 + i) * DDIM + e0 + j], acc[i][j]);
    } else {
        #pragma unroll
        for (int i = 0; i < 4; ++i)
            *(float4*)&base[(d0 + i) * DDIM + e0] =
                make_float4(acc[i][0], acc[i][1], acc[i][2], acc[i][3]);
    }

    // kone: lanes {l, l^16, l^32, l^48} share c4 and cover the wave's 4
    // staged rows -> 2 shfls give per-wave col sums; tiny LDS combine.
    #pragma unroll
    for (int i = 0; i < 4; ++i) {
        k1s[i] += __shfl_xor(k1s[i], 16);
        k1s[i] += __shfl_xor(k1s[i], 32);
    }
    if (l < 16) *(float4*)&koneP[w][c4] = make_float4(k1s[0], k1s[1], k1s[2], k1s[3]);
    __syncthreads();
    if (t < DDIM) {
        const float s1 = koneP[0][t] + koneP[1][t] + koneP[2][t] + koneP[3][t];
        if (ATOMIC) atomicAdd(&base[DDIM * DDIM + t], s1);
        else        base[DDIM * DDIM + t] = s1;
    }
}

// -------- Reduce: fin[i] = sum_c part[c][i]; compile-time NC -> all loads in flight
template<int NCT>
__global__ __launch_bounds__(256) void la_reduce(
    const float* __restrict__ part, float* __restrict__ fin)
{
    const int g = blockIdx.x * 256 + threadIdx.x;     // float4 index
    const float4* p4 = (const float4*)part;
    float4 s = p4[g];
    #pragma unroll
    for (int c = 1; c < NCT; ++c) {
        const float4 v = p4[(size_t)c * (CHUNK_FLOATS / 4) + g];
        s.x += v.x; s.y += v.y; s.z += v.z; s.w += v.w;
    }
    ((float4*)fin)[g] = s;
}

// -------- Phase 2: out[s][e] = (sum_d phiQ[s][d]*kv[d][e]) * mm / (mm*sum_d phiQ[s][d]*kone[d] + 1e-8)
// 256 threads = 4 waves; block covers 128 q-rows. Lane tile 4 rows x 8 cols.
// Per dt: lane loads ONE distinct row, phi's it, publishes to wave-private
// LDS (double-buffered, in-wave DS ordering -> no barrier).
// (256,2): need ~80 regs; (256,4)'s 64-reg grant was mildly spilling.
__global__ __launch_bounds__(256, 2) void la_phase2(
    const float* __restrict__ Q, const float* __restrict__ mask,
    const float* __restrict__ fin_all, float* __restrict__ out)
{
    __shared__ __align__(16) float kvL[DDIM * DDIM];   // 16 KB
    __shared__ __align__(16) float koL[DDIM];
    __shared__ __align__(16) float pqw[4][2][32][4];   // 4 KB phi(Q) staging

    const int bh = blockIdx.y;
    const int b  = bh / HDIM;
    const int t  = threadIdx.x;
    const int w  = t >> 6;
    const int l  = t & 63;
    const int g  = l >> 3;                  // row group 0..7 (4 rows each)
    const int e0 = (l & 7) << 3;
    const int rbase = blockIdx.x * 128 + (w << 5);   // wave's 32 rows
    const int rown  = l & 31;               // row this lane loads (dup for l>=32)

    const float* fin = fin_all + (size_t)bh * BH_STRIDE;
    {
        const float4* src = (const float4*)fin;
        float4* dst = (float4*)kvL;
        #pragma unroll
        for (int k2 = 0; k2 < 4; ++k2) dst[t + 256 * k2] = src[t + 256 * k2];
        if (t < DDIM) koL[t] = fin[DDIM * DDIM + t];
    }

    const float* Qb   = Q + (size_t)bh * SDIM * DDIM;
    const float* mb   = mask + (size_t)b * SDIM;
    const float* Qrow = Qb + (size_t)(rbase + rown) * DDIM;
    const float scale = 0.35355339059327373f;

    // prologue loads overlap the kv-staging barrier
    float4 q0 = *(const float4*)(Qrow);      // dt=0
    float4 qn = *(const float4*)(Qrow + 4);  // dt=1
    __syncthreads();

    // stage dt=0's phi into buf 0 (wave-private; in-wave ordering suffices)
    {
        float4 p;
        p.x = phi_f(q0.x * scale);
        p.y = phi_f(q0.y * scale);
        p.z = phi_f(q0.z * scale);
        p.w = phi_f(q0.w * scale);
        if (l < 32) *(float4*)&pqw[w][0][rown][0] = p;
    }

    float acc[4][8] = {};
    float nrm[4] = {0.f, 0.f, 0.f, 0.f};

    #pragma unroll 1
    for (int dt = 0; dt < 16; ++dt) {
        const int d4  = dt << 2;
        const int cur = dt & 1;
        // stage next dt's phi into the other buffer; prefetch dt+2's Q
        if (dt < 15) {
            float4 p;
            p.x = phi_f(qn.x * scale);
            p.y = phi_f(qn.y * scale);
            p.z = phi_f(qn.z * scale);
            p.w = phi_f(qn.w * scale);
            if (l < 32) *(float4*)&pqw[w][cur ^ 1][rown][0] = p;
            if (dt < 14) qn = *(const float4*)(Qrow + ((dt + 2) << 2));
        }
        // a-rows for this dt (written by this wave at dt-1; in-order DS)
        float4 ar[4];
        #pragma unroll
        for (int i = 0; i < 4; ++i)
            ar[i] = *(const float4*)&pqw[w][cur][(g << 2) + i][0];
        const float4 ko4 = *(const float4*)&koL[d4];
        #pragma unroll
        for (int dd = 0; dd < 4; ++dd) {
            const float4 b0 = *(const float4*)&kvL[(d4 + dd) * DDIM + e0];
            const float4 b1 = *(const float4*)&kvL[(d4 + dd) * DDIM + e0 + 4];
            const float kod = (dd == 0) ? ko4.x : (dd == 1) ? ko4.y : (dd == 2) ? ko4.z : ko4.w;
            #pragma unroll
            for (int i = 0; i < 4; ++i) {
                const float a = (dd == 0) ? ar[i].x : (dd == 1) ? ar[i].y : (dd == 2) ? ar[i].z : ar[i].w;
                nrm[i] += a * kod;
                acc[i][0] += a * b0.x; acc[i][1] += a * b0.y; acc[i][2] += a * b0.z; acc[i][3] += a * b0.w;
                acc[i][4] += a * b1.x; acc[i][5] += a * b1.y; acc[i][6] += a * b1.z; acc[i][7] += a * b1.w;
            }
        }
    }

    // mask folds in exactly: out = mm*A / (mm*B + 1e-8)
    float* ob = out + (size_t)bh * SDIM * DDIM;
    #pragma unroll
    for (int i = 0; i < 4; ++i) {
        const int r  = rbase + (g << 2) + i;
        const float mm  = mb[r];
        const float inv = mm / (mm * nrm[i] + 1e-8f);
        *(float4*)(ob + (size_t)r * DDIM + e0) =
            make_float4(acc[i][0] * inv, acc[i][1] * inv, acc[i][2] * inv, acc[i][3] * inv);
        *(float4*)(ob + (size_t)r * DDIM + e0 + 4) =
            make_float4(acc[i][4] * inv, acc[i][5] * inv, acc[i][6] * inv, acc[i][7] * inv);
    }
}

extern "C" void kernel_launch(void* const* d_in, const int* in_sizes, int n_in,
                              void* d_out, int out_size, void* d_ws, size_t ws_size,
                              hipStream_t stream) {
    const float* Q = (const float*)d_in[0];
    const float* K = (const float*)d_in[1];
    const float* V = (const float*)d_in[2];
    const float* M = (const float*)d_in[3];
    float* out = (float*)d_out;

    const size_t chunk_bytes = (size_t)CHUNK_FLOATS * sizeof(float);  // 1,064,960 B

    // ws_size is constant across calls -> same path every call (graph-safe)
    if (ws_size >= 33 * chunk_bytes) {          // 35.1 MB: 32 partials + final
        float* part = (float*)d_ws;
        float* fin  = part + (size_t)32 * CHUNK_FLOATS;
        la_phase1<false><<<dim3(32, NBH), dim3(256), 0, stream>>>(K, V, M, part, SDIM / 32);
        la_reduce<32><<<dim3(CHUNK_FLOATS / 4 / 256), dim3(256), 0, stream>>>(part, fin);
        la_phase2<<<dim3(SDIM / 128, NBH), dim3(256), 0, stream>>>(Q, M, fin, out);
    } else if (ws_size >= 17 * chunk_bytes) {   // 18.1 MB: 16 partials + final
        float* part = (float*)d_ws;
        float* fin  = part + (size_t)16 * CHUNK_FLOATS;
        la_phase1<false><<<dim3(16, NBH), dim3(256), 0, stream>>>(K, V, M, part, SDIM / 16);
        la_reduce<16><<<dim3(CHUNK_FLOATS / 4 / 256), dim3(256), 0, stream>>>(part, fin);
        la_phase2<<<dim3(SDIM / 128, NBH), dim3(256), 0, stream>>>(Q, M, fin, out);
    } else {
        // fallback: atomic accumulation directly into final buffer (1.06 MB)
        float* fin = (float*)d_ws;
        hipMemsetAsync(d_ws, 0, chunk_bytes, stream);
        la_phase1<true><<<dim3(16, NBH), dim3(256), 0, stream>>>(K, V, M, fin, SDIM / 16);
        la_phase2<<<dim3(SDIM / 128, NBH), dim3(256), 0, stream>>>(Q, M, fin, out);
    }
}